// Round 4
// baseline (79.891 us; speedup 1.0000x reference)
//
#include <hip/hip_runtime.h>
#include <math.h>

#define BSZ   65536
#define INP   16
#define HL    10
#define NL    3
#define TT    200
#define NPOP  8600000.0f

#define CH    16           // steps per chunk
#define NCH   12           // 12*16 = 192 full-chunk steps
#define TAIL  7            // 199 - 192

__global__ __launch_bounds__(256, 1) void sir_kernel(
    const float* __restrict__ data,   // B x IN
    const float* __restrict__ times,  // T
    const float* __restrict__ W0,     // 3 x HL x IN
    const float* __restrict__ b0,     // 3 x HL
    const float* __restrict__ Wh,     // 3 x NL x HL x HL
    const float* __restrict__ bh,     // 3 x NL x HL
    const float* __restrict__ Wo,     // 3 x 1 x HL
    const float* __restrict__ bo,     // 3 x 1
    float* __restrict__ out)          // T x B
{
    __shared__ float sdt[TT];            // dt table
    __shared__ float slab[2][CH][256];   // I-value staging, double-buffered

    const int tid = threadIdx.x;
    if (tid < TT - 1) sdt[tid] = times[tid + 1] - times[tid];
    if (tid == TT - 1) sdt[tid] = 0.0f;
    __syncthreads();

    const int b = blockIdx.x * 256 + tid;

    // ---- input row: 4x float4, coalesced ----
    float x[INP];
    const float4* xin = reinterpret_cast<const float4*>(data + (size_t)b * INP);
    #pragma unroll
    for (int q = 0; q < INP / 4; ++q) {
        float4 v = xin[q];
        x[q * 4 + 0] = v.x; x[q * 4 + 1] = v.y;
        x[q * 4 + 2] = v.z; x[q * 4 + 3] = v.w;
    }

    // ---- three parameter nets (weights uniform -> scalar loads) ----
    float vals[3];
    #pragma unroll 1
    for (int n = 0; n < 3; ++n) {
        float h[HL];
        #pragma unroll
        for (int k = 0; k < HL; ++k) {
            float acc = b0[n * HL + k];
            #pragma unroll
            for (int i = 0; i < INP; ++i)
                acc = fmaf(x[i], W0[(n * HL + k) * INP + i], acc);
            h[k] = tanhf(acc);
        }
        #pragma unroll 1
        for (int l = 0; l < NL; ++l) {
            float h2[HL];
            #pragma unroll
            for (int k = 0; k < HL; ++k) {
                float acc = bh[(n * NL + l) * HL + k];
                #pragma unroll
                for (int i = 0; i < HL; ++i)
                    acc = fmaf(h[i], Wh[((n * NL + l) * HL + k) * HL + i], acc);
                h2[k] = tanhf(acc);
            }
            #pragma unroll
            for (int k = 0; k < HL; ++k) h[k] = h2[k];
        }
        float acc = bo[n];
        #pragma unroll
        for (int i = 0; i < HL; ++i)
            acc = fmaf(h[i], Wo[n * HL + i], acc);
        vals[n] = fmaxf(acc, 0.0f) + log1pf(expf(-fabsf(acc)));  // stable softplus
    }

    const float gamma = vals[0];
    const float beta  = vals[1];
    const float I0    = vals[2];

    float S = NPOP - I0;
    float I = I0;
    const float bn = beta * (1.0f / NPOP);

    out[b] = I;   // t = 0

    auto step = [&](float dt) {
        const float hdt = 0.5f * dt;
        float flux, rec;
        flux = bn * S * I;  rec = gamma * I;
        const float k1S = -flux, k1I = flux - rec;
        float aS = fmaf(hdt, k1S, S), aI = fmaf(hdt, k1I, I);
        flux = bn * aS * aI;  rec = gamma * aI;
        const float k2S = -flux, k2I = flux - rec;
        aS = fmaf(hdt, k2S, S);  aI = fmaf(hdt, k2I, I);
        flux = bn * aS * aI;  rec = gamma * aI;
        const float k3S = -flux, k3I = flux - rec;
        aS = fmaf(dt, k3S, S);  aI = fmaf(dt, k3I, I);
        flux = bn * aS * aI;  rec = gamma * aI;
        const float k4S = -flux, k4I = flux - rec;
        const float c = dt * (1.0f / 6.0f);
        S = fmaf(c, k1S + 2.0f * k2S + 2.0f * k3S + k4S, S);
        I = fmaf(c, k1I + 2.0f * k2I + 2.0f * k3I + k4I, I);
    };

    const float4* sdt4 = reinterpret_cast<const float4*>(sdt);

    // ---- 12 chunks of 16 pure-ALU steps; I staged through LDS ----
    #pragma unroll 1
    for (int c2 = 0; c2 < NCH; ++c2) {
        const int t0 = c2 * CH;
        const int p  = c2 & 1;

        // hoisted chunk dts: 4x float4 LDS broadcast reads
        float d[CH];
        #pragma unroll
        for (int q = 0; q < CH / 4; ++q) {
            float4 v = sdt4[t0 / 4 + q];
            d[q * 4 + 0] = v.x; d[q * 4 + 1] = v.y;
            d[q * 4 + 2] = v.z; d[q * 4 + 3] = v.w;
        }

        // compute: ds_write is fire-and-forget, keeps the S/I chain off vmcnt
        #pragma unroll
        for (int u = 0; u < CH; ++u) {
            step(d[u]);
            slab[p][u][tid] = I;
        }

        // burst: volatile LDS reads (no store-to-load forwarding) -> 16 stores
        #pragma unroll
        for (int u = 0; u < CH; ++u) {
            const float v = *(volatile const float*)&slab[p][u][tid];
            out[(size_t)(t0 + u + 1) * BSZ + b] = v;
        }
    }

    // ---- tail: 7 steps ----
    {
        const int t0 = NCH * CH;
        float d[TAIL];
        #pragma unroll
        for (int u = 0; u < TAIL; ++u) d[u] = sdt[t0 + u];

        #pragma unroll
        for (int u = 0; u < TAIL; ++u) {
            step(d[u]);
            slab[0][u][tid] = I;
        }
        #pragma unroll
        for (int u = 0; u < TAIL; ++u) {
            const float v = *(volatile const float*)&slab[0][u][tid];
            out[(size_t)(t0 + u + 1) * BSZ + b] = v;
        }
    }
}

extern "C" void kernel_launch(void* const* d_in, const int* in_sizes, int n_in,
                              void* d_out, int out_size, void* d_ws, size_t ws_size,
                              hipStream_t stream) {
    const float* data  = (const float*)d_in[0];
    const float* times = (const float*)d_in[1];
    const float* W0    = (const float*)d_in[2];
    const float* b0    = (const float*)d_in[3];
    const float* Wh    = (const float*)d_in[4];
    const float* bh    = (const float*)d_in[5];
    const float* Wo    = (const float*)d_in[6];
    const float* bo    = (const float*)d_in[7];
    float* out = (float*)d_out;

    sir_kernel<<<BSZ / 256, 256, 0, stream>>>(data, times, W0, b0, Wh, bh, Wo, bo, out);
}

// Round 5
// 42.706 us; speedup vs baseline: 1.8707x; 1.8707x over previous
//
#include <hip/hip_runtime.h>
#include <math.h>

#define BSZ   65536
#define INP   16
#define HL    10
#define NL    3
#define TT    200
#define NPOP  8600000.0f

// 199 steps = 24 chunks of 8 + tail of 7
#define NCH8  24

__device__ __forceinline__ float fast_tanh(float x) {
    // tanh(x) = 1 - 2/(e^{2x}+1);  exp2f -> v_exp_f32, rcp -> v_rcp_f32 (~1ulp)
    float e = exp2f(x * 2.8853900817779268f);
    return 1.0f - 2.0f * __builtin_amdgcn_rcpf(e + 1.0f);
}

__global__ __launch_bounds__(256, 1) void sir_kernel(
    const float* __restrict__ data,   // B x IN
    const float* __restrict__ times,  // T
    const float* __restrict__ W0,     // 3 x HL x IN
    const float* __restrict__ b0,     // 3 x HL
    const float* __restrict__ Wh,     // 3 x NL x HL x HL
    const float* __restrict__ bh,     // 3 x NL x HL
    const float* __restrict__ Wo,     // 3 x 1 x HL
    const float* __restrict__ bo,     // 3 x 1
    float* __restrict__ out)          // T x B
{
    __shared__ float sdt[208];        // dt table, padded to 52 float4s, zeros past 198

    const int tid = threadIdx.x;
    if (tid < TT - 1)                sdt[tid] = times[tid + 1] - times[tid];
    else if (tid < 208)              sdt[tid] = 0.0f;
    __syncthreads();

    const int b = blockIdx.x * 256 + tid;

    // ---- input row: 4x float4, coalesced ----
    float x[INP];
    const float4* xin = reinterpret_cast<const float4*>(data + (size_t)b * INP);
    #pragma unroll
    for (int q = 0; q < INP / 4; ++q) {
        float4 v = xin[q];
        x[q * 4 + 0] = v.x; x[q * 4 + 1] = v.y;
        x[q * 4 + 2] = v.z; x[q * 4 + 3] = v.w;
    }

    // ---- three parameter nets (weights uniform -> scalar loads) ----
    float vals[3];
    #pragma unroll 1
    for (int n = 0; n < 3; ++n) {
        float h[HL];
        #pragma unroll
        for (int k = 0; k < HL; ++k) {
            float acc = b0[n * HL + k];
            #pragma unroll
            for (int i = 0; i < INP; ++i)
                acc = fmaf(x[i], W0[(n * HL + k) * INP + i], acc);
            h[k] = fast_tanh(acc);
        }
        #pragma unroll 1
        for (int l = 0; l < NL; ++l) {
            float h2[HL];
            #pragma unroll
            for (int k = 0; k < HL; ++k) {
                float acc = bh[(n * NL + l) * HL + k];
                #pragma unroll
                for (int i = 0; i < HL; ++i)
                    acc = fmaf(h[i], Wh[((n * NL + l) * HL + k) * HL + i], acc);
                h2[k] = fast_tanh(acc);
            }
            #pragma unroll
            for (int k = 0; k < HL; ++k) h[k] = h2[k];
        }
        float acc = bo[n];
        #pragma unroll
        for (int i = 0; i < HL; ++i)
            acc = fmaf(h[i], Wo[n * HL + i], acc);
        vals[n] = fmaxf(acc, 0.0f) + log1pf(expf(-fabsf(acc)));  // stable softplus
    }

    const float gamma = vals[0];
    const float beta  = vals[1];
    const float I0    = vals[2];

    float S = NPOP - I0;
    float I = I0;
    const float bn = beta * (1.0f / NPOP);

    out[b] = I;   // t = 0

    auto step = [&](float dt) {
        const float hdt = 0.5f * dt;
        float flux, rec;
        flux = bn * S * I;  rec = gamma * I;
        const float k1S = -flux, k1I = flux - rec;
        float aS = fmaf(hdt, k1S, S), aI = fmaf(hdt, k1I, I);
        flux = bn * aS * aI;  rec = gamma * aI;
        const float k2S = -flux, k2I = flux - rec;
        aS = fmaf(hdt, k2S, S);  aI = fmaf(hdt, k2I, I);
        flux = bn * aS * aI;  rec = gamma * aI;
        const float k3S = -flux, k3I = flux - rec;
        aS = fmaf(dt, k3S, S);  aI = fmaf(dt, k3I, I);
        flux = bn * aS * aI;  rec = gamma * aI;
        const float k4S = -flux, k4I = flux - rec;
        const float c = dt * (1.0f / 6.0f);
        S = fmaf(c, k1S + 2.0f * k2S + 2.0f * k3S + k4S, S);
        I = fmaf(c, k1I + 2.0f * k2I + 2.0f * k3I + k4I, I);
    };

    const float4* sdt4 = reinterpret_cast<const float4*>(sdt);

    float4 da = sdt4[0];
    float4 db = sdt4[1];
    float* op = out + BSZ;            // row t = 1

    #pragma unroll 1
    for (int g = 0; g < NCH8; ++g) {
        // prefetch next chunk's dts; lgkm wait lands at the da/db copy below
        float4 na = sdt4[2 * g + 2];
        float4 nb = sdt4[2 * g + 3];
        __builtin_amdgcn_sched_barrier(0);   // pin prefetch above the step block

        float ic0, ic1, ic2, ic3, ic4, ic5, ic6, ic7;
        step(da.x); ic0 = I; op[b          ] = ic0;
        step(da.y); ic1 = I; op[b + 1 * BSZ] = ic1;
        step(da.z); ic2 = I; op[b + 2 * BSZ] = ic2;
        step(da.w); ic3 = I; op[b + 3 * BSZ] = ic3;
        step(db.x); ic4 = I; op[b + 4 * BSZ] = ic4;
        step(db.y); ic5 = I; op[b + 5 * BSZ] = ic5;
        step(db.z); ic6 = I; op[b + 6 * BSZ] = ic6;
        step(db.w); ic7 = I; op[b + 7 * BSZ] = ic7;

        // keep all 8 store-data values simultaneously live -> 8 distinct VGPRs,
        // register-reuse distance ~7 steps, vmcnt waits pre-satisfied
        asm volatile("" :: "v"(ic0), "v"(ic1), "v"(ic2), "v"(ic3),
                           "v"(ic4), "v"(ic5), "v"(ic6), "v"(ic7));

        da = na; db = nb;
        op += 8 * BSZ;
    }

    // ---- tail: 7 steps (t = 192..198) ----
    {
        float d0 = sdt[192], d1 = sdt[193], d2 = sdt[194], d3 = sdt[195];
        float d4 = sdt[196], d5 = sdt[197], d6 = sdt[198];
        float ic0, ic1, ic2, ic3, ic4, ic5, ic6;
        step(d0); ic0 = I; op[b          ] = ic0;
        step(d1); ic1 = I; op[b + 1 * BSZ] = ic1;
        step(d2); ic2 = I; op[b + 2 * BSZ] = ic2;
        step(d3); ic3 = I; op[b + 3 * BSZ] = ic3;
        step(d4); ic4 = I; op[b + 4 * BSZ] = ic4;
        step(d5); ic5 = I; op[b + 5 * BSZ] = ic5;
        step(d6); ic6 = I; op[b + 6 * BSZ] = ic6;
        asm volatile("" :: "v"(ic0), "v"(ic1), "v"(ic2), "v"(ic3),
                           "v"(ic4), "v"(ic5), "v"(ic6));
    }
}

extern "C" void kernel_launch(void* const* d_in, const int* in_sizes, int n_in,
                              void* d_out, int out_size, void* d_ws, size_t ws_size,
                              hipStream_t stream) {
    const float* data  = (const float*)d_in[0];
    const float* times = (const float*)d_in[1];
    const float* W0    = (const float*)d_in[2];
    const float* b0    = (const float*)d_in[3];
    const float* Wh    = (const float*)d_in[4];
    const float* bh    = (const float*)d_in[5];
    const float* Wo    = (const float*)d_in[6];
    const float* bo    = (const float*)d_in[7];
    float* out = (float*)d_out;

    sir_kernel<<<BSZ / 256, 256, 0, stream>>>(data, times, W0, b0, Wh, bh, Wo, bo, out);
}

// Round 6
// 32.004 us; speedup vs baseline: 2.4963x; 1.3344x over previous
//
#include <hip/hip_runtime.h>
#include <math.h>

#define BSZ   65536
#define INP   16
#define HL    10
#define NL    3
#define TT    200
#define NPOP  8600000.0f

#define NCH8  24   // 24 chunks of 8 steps + tail of 7 = 199

__device__ __forceinline__ float fast_tanh(float x) {
    float e = exp2f(x * 2.8853900817779268f);
    return 1.0f - 2.0f * __builtin_amdgcn_rcpf(e + 1.0f);
}

// ---------------- Kernel A: parameter nets, one thread per (sample, net) ----
__global__ __launch_bounds__(256) void mlp_kernel(
    const float* __restrict__ data,   // B x IN
    const float* __restrict__ W0,     // 3 x HL x IN
    const float* __restrict__ b0,     // 3 x HL
    const float* __restrict__ Wh,     // 3 x NL x HL x HL
    const float* __restrict__ bh,     // 3 x NL x HL
    const float* __restrict__ Wo,     // 3 x 1 x HL
    const float* __restrict__ bo,     // 3 x 1
    float* __restrict__ vals)         // 3 x B  (gamma row, beta row, I0 row)
{
    const int n   = blockIdx.y;       // which net
    const int tid = threadIdx.x;

    __shared__ float sW0[HL * INP];
    __shared__ float sb0[HL];
    __shared__ float sWh[NL * HL * HL];
    __shared__ float sbh[NL * HL];
    __shared__ float sWo[HL];
    __shared__ float sbo;

    for (int i = tid; i < HL * INP;      i += 256) sW0[i] = W0[n * HL * INP + i];
    for (int i = tid; i < HL;            i += 256) sb0[i] = b0[n * HL + i];
    for (int i = tid; i < NL * HL * HL;  i += 256) sWh[i] = Wh[n * NL * HL * HL + i];
    for (int i = tid; i < NL * HL;       i += 256) sbh[i] = bh[n * NL * HL + i];
    for (int i = tid; i < HL;            i += 256) sWo[i] = Wo[n * HL + i];
    if (tid == 0) sbo = bo[n];
    __syncthreads();

    const int b = blockIdx.x * 256 + tid;

    float x[INP];
    const float4* xin = reinterpret_cast<const float4*>(data + (size_t)b * INP);
    #pragma unroll
    for (int q = 0; q < INP / 4; ++q) {
        float4 v = xin[q];
        x[q * 4 + 0] = v.x; x[q * 4 + 1] = v.y;
        x[q * 4 + 2] = v.z; x[q * 4 + 3] = v.w;
    }

    float h[HL];
    #pragma unroll
    for (int k = 0; k < HL; ++k) {
        float acc = sb0[k];
        #pragma unroll
        for (int i = 0; i < INP; ++i)
            acc = fmaf(x[i], sW0[k * INP + i], acc);
        h[k] = fast_tanh(acc);
    }
    #pragma unroll
    for (int l = 0; l < NL; ++l) {
        float h2[HL];
        #pragma unroll
        for (int k = 0; k < HL; ++k) {
            float acc = sbh[l * HL + k];
            #pragma unroll
            for (int i = 0; i < HL; ++i)
                acc = fmaf(h[i], sWh[(l * HL + k) * HL + i], acc);
            h2[k] = fast_tanh(acc);
        }
        #pragma unroll
        for (int k = 0; k < HL; ++k) h[k] = h2[k];
    }
    float acc = sbo;
    #pragma unroll
    for (int i = 0; i < HL; ++i)
        acc = fmaf(h[i], sWo[i], acc);

    // stable softplus
    vals[(size_t)n * BSZ + b] = fmaxf(acc, 0.0f) + log1pf(expf(-fabsf(acc)));
}

// ---------------- Kernel B: RK4 integration, one thread per sample ----------
__global__ __launch_bounds__(256, 1) void sir_kernel(
    const float* __restrict__ vals,   // 3 x B
    const float* __restrict__ times,  // T
    float* __restrict__ out)          // T x B
{
    const int tid = threadIdx.x;
    const int b = blockIdx.x * 256 + tid;

    // issue param loads early; they complete while we stage dts
    const float gamma = vals[b];
    const float beta  = vals[BSZ + b];
    const float I0    = vals[2 * BSZ + b];

    __shared__ float sdt[208];        // 52 float4s, zero-padded past 198
    if (tid < TT - 1)       sdt[tid] = times[tid + 1] - times[tid];
    else if (tid < 208)     sdt[tid] = 0.0f;
    __syncthreads();

    float S = NPOP - I0;
    float I = I0;
    const float bn = beta * (1.0f / NPOP);

    out[b] = I;   // t = 0

    // folded RK4 step: negations absorbed into fma coefficients
    auto step = [&](float dt) {
        const float hdt = 0.5f * dt;
        float f1 = (bn * S) * I;
        float r1 = gamma * I;
        float m1 = f1 - r1;
        float aS = fmaf(-hdt, f1, S), aI = fmaf(hdt, m1, I);
        float f2 = (bn * aS) * aI;
        float r2 = gamma * aI;
        float m2 = f2 - r2;
        float bS = fmaf(-hdt, f2, S), bI = fmaf(hdt, m2, I);
        float f3 = (bn * bS) * bI;
        float r3 = gamma * bI;
        float m3 = f3 - r3;
        float cS = fmaf(-dt, f3, S),  cI = fmaf(dt, m3, I);
        float f4 = (bn * cS) * cI;
        float r4 = gamma * cI;
        float m4 = f4 - r4;
        const float c6 = dt * (1.0f / 6.0f);
        S = fmaf(-c6, (f1 + f4) + 2.0f * (f2 + f3), S);
        I = fmaf( c6, (m1 + m4) + 2.0f * (m2 + m3), I);
    };

    const float4* sdt4 = reinterpret_cast<const float4*>(sdt);

    float4 da = sdt4[0];
    float4 db = sdt4[1];
    float* op = out + BSZ;            // row t = 1

    #pragma unroll 1
    for (int g = 0; g < NCH8; ++g) {
        float4 na = sdt4[2 * g + 2];
        float4 nb = sdt4[2 * g + 3];
        __builtin_amdgcn_sched_barrier(0);   // pin prefetch above the step block

        float ic0, ic1, ic2, ic3, ic4, ic5, ic6, ic7;
        step(da.x); ic0 = I; op[b          ] = ic0;
        step(da.y); ic1 = I; op[b + 1 * BSZ] = ic1;
        step(da.z); ic2 = I; op[b + 2 * BSZ] = ic2;
        step(da.w); ic3 = I; op[b + 3 * BSZ] = ic3;
        step(db.x); ic4 = I; op[b + 4 * BSZ] = ic4;
        step(db.y); ic5 = I; op[b + 5 * BSZ] = ic5;
        step(db.z); ic6 = I; op[b + 6 * BSZ] = ic6;
        step(db.w); ic7 = I; op[b + 7 * BSZ] = ic7;

        // 8 distinct live store-data regs -> reuse distance ~7 steps
        asm volatile("" :: "v"(ic0), "v"(ic1), "v"(ic2), "v"(ic3),
                           "v"(ic4), "v"(ic5), "v"(ic6), "v"(ic7));

        da = na; db = nb;
        op += 8 * BSZ;
    }

    // tail: 7 steps (t = 192..198)
    {
        float d0 = sdt[192], d1 = sdt[193], d2 = sdt[194], d3 = sdt[195];
        float d4 = sdt[196], d5 = sdt[197], d6 = sdt[198];
        float ic0, ic1, ic2, ic3, ic4, ic5, ic6;
        step(d0); ic0 = I; op[b          ] = ic0;
        step(d1); ic1 = I; op[b + 1 * BSZ] = ic1;
        step(d2); ic2 = I; op[b + 2 * BSZ] = ic2;
        step(d3); ic3 = I; op[b + 3 * BSZ] = ic3;
        step(d4); ic4 = I; op[b + 4 * BSZ] = ic4;
        step(d5); ic5 = I; op[b + 5 * BSZ] = ic5;
        step(d6); ic6 = I; op[b + 6 * BSZ] = ic6;
        asm volatile("" :: "v"(ic0), "v"(ic1), "v"(ic2), "v"(ic3),
                           "v"(ic4), "v"(ic5), "v"(ic6));
    }
}

extern "C" void kernel_launch(void* const* d_in, const int* in_sizes, int n_in,
                              void* d_out, int out_size, void* d_ws, size_t ws_size,
                              hipStream_t stream) {
    const float* data  = (const float*)d_in[0];
    const float* times = (const float*)d_in[1];
    const float* W0    = (const float*)d_in[2];
    const float* b0    = (const float*)d_in[3];
    const float* Wh    = (const float*)d_in[4];
    const float* bh    = (const float*)d_in[5];
    const float* Wo    = (const float*)d_in[6];
    const float* bo    = (const float*)d_in[7];
    float* out  = (float*)d_out;
    float* vals = (float*)d_ws;       // 3 * BSZ floats = 768 KB

    dim3 gridA(BSZ / 256, 3);
    mlp_kernel<<<gridA, 256, 0, stream>>>(data, W0, b0, Wh, bh, Wo, bo, vals);
    sir_kernel<<<BSZ / 256, 256, 0, stream>>>(vals, times, out);
}